// Round 13
// baseline (1048.952 us; speedup 1.0000x reference)
//
#include <hip/hip_runtime.h>
#include <hip/hip_bf16.h>

#define NNODES 8192
#define EMB    1024
#define HID    256
#define MAXDEG 128

typedef float f32x4 __attribute__((ext_vector_type(4)));
typedef short bf16x8v __attribute__((ext_vector_type(8)));
typedef unsigned short u16x4 __attribute__((ext_vector_type(4)));
typedef unsigned short u16x8 __attribute__((ext_vector_type(8)));

static __device__ __forceinline__ unsigned short f2bf(float f) {
  union { float f; unsigned int u; } x; x.f = f;
  unsigned int r = (x.u + 0x7fffu + ((x.u >> 16) & 1u)) >> 16;
  return (unsigned short)r;
}
static __device__ __forceinline__ float bf2f(unsigned short u) {
  union { unsigned int u; float f; } x; x.u = ((unsigned int)u) << 16;
  return x.f;
}

// ---------------------------------------------------------------------------
// Prep: Wt[n][k] = bf16(W[k][n]); zero the barrier counter.
// ---------------------------------------------------------------------------
__global__ __launch_bounds__(256) void prep_wt(const float* __restrict__ W,
                                               unsigned short* __restrict__ Wt,
                                               unsigned int* __restrict__ cnt) {
  if (blockIdx.x == 0 && threadIdx.x == 0) *cnt = 0u;
  __shared__ float lds[64 * 65];
  int k0 = (blockIdx.x >> 2) * 64;
  int n0 = (blockIdx.x & 3) * 64;
  int t = threadIdx.x;
#pragma unroll
  for (int p = 0; p < 4; p++) {
    int k = p * 16 + (t >> 4);
    int c4 = (t & 15) * 4;
    float4 v = *(const float4*)&W[(size_t)(k0 + k) * HID + n0 + c4];
    lds[k * 65 + c4 + 0] = v.x; lds[k * 65 + c4 + 1] = v.y;
    lds[k * 65 + c4 + 2] = v.z; lds[k * 65 + c4 + 3] = v.w;
  }
  __syncthreads();
  int n = t >> 2, kq = t & 3;
  u16x8 o0, o1;
#pragma unroll
  for (int i = 0; i < 8; i++) o0[i] = f2bf(lds[(kq * 16 + i) * 65 + n]);
#pragma unroll
  for (int i = 0; i < 8; i++) o1[i] = f2bf(lds[(kq * 16 + 8 + i) * 65 + n]);
  unsigned short* dst = &Wt[(size_t)(n0 + n) * EMB + k0 + kq * 16];
  *(u16x8*)(dst) = o0;
  *(u16x8*)(dst + 8) = o1;
}

// ---------------------------------------------------------------------------
// Fused (R12 verbatim): blocks [0,256) = bf16-MFMA GEMM 128x64 tile;
// blocks [256, 256+8192) = adjacency extract with nontemporal loads.
// ---------------------------------------------------------------------------
#define GEMM_BLOCKS 256

__global__ __launch_bounds__(256) void fused_extract_gemm(
    const float* __restrict__ X, const unsigned short* __restrict__ Wt,
    const float* __restrict__ bias, const float* __restrict__ adj,
    unsigned short* __restrict__ hb0, float* __restrict__ dinv,
    int* __restrict__ nnz, int* __restrict__ cols, float* __restrict__ vals) {
  __shared__ char smem[24 * 1024 + 64];
  int t = threadIdx.x;

  if (blockIdx.x >= GEMM_BLOCKS) {
    int row = blockIdx.x - GEMM_BLOCKS;
    int* s_cnt = (int*)smem;
    float* s_part = (float*)(smem + 16);
    if (t == 0) *s_cnt = 0;
    __syncthreads();
    const f32x4* arow = (const f32x4*)(adj + (size_t)row * NNODES);
    float sum = 0.f;
    int base = row * MAXDEG;
    for (int c4 = t; c4 < NNODES / 4; c4 += 256) {
      f32x4 v = __builtin_nontemporal_load(arow + c4);
      sum += v.x + v.y + v.z + v.w;
      if (v.x != 0.f) { int p = atomicAdd(s_cnt, 1); if (p < MAXDEG) { cols[base + p] = c4 * 4 + 0; vals[base + p] = v.x; } }
      if (v.y != 0.f) { int p = atomicAdd(s_cnt, 1); if (p < MAXDEG) { cols[base + p] = c4 * 4 + 1; vals[base + p] = v.y; } }
      if (v.z != 0.f) { int p = atomicAdd(s_cnt, 1); if (p < MAXDEG) { cols[base + p] = c4 * 4 + 2; vals[base + p] = v.z; } }
      if (v.w != 0.f) { int p = atomicAdd(s_cnt, 1); if (p < MAXDEG) { cols[base + p] = c4 * 4 + 3; vals[base + p] = v.w; } }
    }
    for (int off = 32; off > 0; off >>= 1) sum += __shfl_down(sum, off, 64);
    int wave = t >> 6;
    if ((t & 63) == 0) s_part[wave] = sum;
    __syncthreads();
    if (t == 0) {
      float tot = s_part[0] + s_part[1] + s_part[2] + s_part[3];
      dinv[row] = rsqrtf(tot);
      int c = *s_cnt;
      nnz[row] = (c > MAXDEG) ? MAXDEG : c;
    }
    return;
  }

  unsigned short* As = (unsigned short*)smem;               // [128][64] bf16
  unsigned short* Bs = (unsigned short*)(smem + 16 * 1024); // [64][64] bf16 (B^T)
  int mb = blockIdx.x >> 2, nb = blockIdx.x & 3;
  int m0 = mb * 128, n0 = nb * 64;
  int w = t >> 6, l = t & 63;

  f32x4 acc[2][4] = {};

  for (int kt = 0; kt < EMB; kt += 64) {
    __syncthreads();
    {
      int c4 = t & 15;
#pragma unroll
      for (int rr = 0; rr < 8; rr++) {
        int row = rr * 16 + (t >> 4);
        float4 v = *(const float4*)&X[(size_t)(m0 + row) * EMB + kt + c4 * 4];
        u16x4 pk = {f2bf(v.x), f2bf(v.y), f2bf(v.z), f2bf(v.w)};
        int slot = ((c4 >> 1) + (row >> 1)) & 7;
        *(u16x4*)&As[row * 64 + slot * 8 + (c4 & 1) * 4] = pk;
      }
    }
    {
      int n = t >> 2, q = t & 3;
      const unsigned short* src = &Wt[(size_t)(n0 + n) * EMB + kt + q * 16];
#pragma unroll
      for (int e = 0; e < 2; e++) {
        u16x8 v = *(const u16x8*)(src + e * 8);
        int slot = ((q * 2 + e) + (n >> 1)) & 7;
        *(u16x8*)&Bs[n * 64 + slot * 8] = v;
      }
    }
    __syncthreads();
#pragma unroll
    for (int ks = 0; ks < 2; ks++) {
      bf16x8v a[2], b[4];
#pragma unroll
      for (int mf = 0; mf < 2; mf++) {
        int row = w * 32 + mf * 16 + (l & 15);
        int slot = ((ks * 4 + (l >> 4)) + (row >> 1)) & 7;
        a[mf] = *(bf16x8v*)&As[row * 64 + slot * 8];
      }
#pragma unroll
      for (int nf = 0; nf < 4; nf++) {
        int rowB = nf * 16 + (l & 15);
        int slot = ((ks * 4 + (l >> 4)) + (rowB >> 1)) & 7;
        b[nf] = *(bf16x8v*)&Bs[rowB * 64 + slot * 8];
      }
#pragma unroll
      for (int mf = 0; mf < 2; mf++)
#pragma unroll
        for (int nf = 0; nf < 4; nf++)
          acc[mf][nf] = __builtin_amdgcn_mfma_f32_16x16x32_bf16(a[mf], b[nf], acc[mf][nf], 0, 0, 0);
    }
  }
#pragma unroll
  for (int mf = 0; mf < 2; mf++)
#pragma unroll
    for (int nf = 0; nf < 4; nf++) {
      int r0 = m0 + w * 32 + mf * 16 + (l >> 4) * 4;
      int cc = n0 + nf * 16 + (l & 15);
      float bv = bias[cc];
#pragma unroll
      for (int r = 0; r < 4; r++)
        hb0[(size_t)(r0 + r) * HID + cc] = f2bf(fmaxf(acc[mf][nf][r] + bv, 0.f));
    }
}

// ---------------------------------------------------------------------------
// Persistent propagation: all 6 APPNP steps in one kernel.
// 256 blocks x 256 threads (1 block/CU -> co-resident on idle GPU; REGULAR
// launch). Hand-rolled device barrier: monotonic counter, release add +
// acquire poll, bounded spin (breaks rather than hangs). Per-step math is
// bit-identical to R12's prop_bf16/prop_final. No __restrict__ on the
// ping-pong buffers (each is accessed through multiple names across steps).
// ---------------------------------------------------------------------------
#define PROP_BLOCKS 256

__global__ __launch_bounds__(256) void prop_persist(
    const unsigned short* hb0, unsigned short* hb1, unsigned short* hb2,
    float* out, const float* dinv, const int* nnz, const int* cols,
    const float* vals, unsigned int* cnt) {
  int w = threadIdx.x >> 6, l = threadIdx.x & 63;
  int rbase = (blockIdx.x * 4 + w) * 8;   // 8 rows per wave

  for (int s = 0; s < 6; s++) {
    const unsigned short* src = (s == 0) ? hb0 : ((s & 1) ? hb1 : hb2);
    unsigned short* dst = (s & 1) ? hb2 : hb1;

    for (int r = 0; r < 8; r++) {
      int row = rbase + r;
      int n = nnz[row];
      int base = row * MAXDEG;
      float ax = 0.f, ay = 0.f, az = 0.f, aw = 0.f;
      for (int k = 0; k < n; k++) {
        int j = cols[base + k];
        float wgt = vals[base + k] * dinv[j];
        u16x4 hv = *(const u16x4*)&src[(size_t)j * HID + l * 4];
        ax += wgt * bf2f(hv[0]); ay += wgt * bf2f(hv[1]);
        az += wgt * bf2f(hv[2]); aw += wgt * bf2f(hv[3]);
      }
      float sc = 0.8f * dinv[row];
      u16x4 h0v = *(const u16x4*)&hb0[(size_t)row * HID + l * 4];
      if (s < 5) {
        u16x4 o;
        o[0] = f2bf(sc * ax + 0.2f * bf2f(h0v[0]));
        o[1] = f2bf(sc * ay + 0.2f * bf2f(h0v[1]));
        o[2] = f2bf(sc * az + 0.2f * bf2f(h0v[2]));
        o[3] = f2bf(sc * aw + 0.2f * bf2f(h0v[3]));
        *(u16x4*)&dst[(size_t)row * HID + l * 4] = o;
      } else {
        float4 o;
        o.x = sc * ax + 0.2f * bf2f(h0v[0]);
        o.y = sc * ay + 0.2f * bf2f(h0v[1]);
        o.z = sc * az + 0.2f * bf2f(h0v[2]);
        o.w = sc * aw + 0.2f * bf2f(h0v[3]);
        *(float4*)&out[(size_t)row * HID + l * 4] = o;
      }
    }

    if (s < 5) {
      // ---- device barrier ----
      __syncthreads();
      if (threadIdx.x == 0) {
        __threadfence();   // release: make this block's stores device-visible
        __hip_atomic_fetch_add(cnt, 1u, __ATOMIC_RELEASE,
                               __HIP_MEMORY_SCOPE_AGENT);
        unsigned int target = (unsigned int)PROP_BLOCKS * (unsigned int)(s + 1);
        unsigned int it = 0;
        while (__hip_atomic_load(cnt, __ATOMIC_ACQUIRE,
                                 __HIP_MEMORY_SCOPE_AGENT) < target) {
          if (++it > (1u << 24)) break;   // bounded: fail, don't hang
          __builtin_amdgcn_s_sleep(2);
        }
        __threadfence();   // acquire: invalidate stale lines before reads
      }
      __syncthreads();
    }
  }
}

// ---------------------------------------------------------------------------
extern "C" void kernel_launch(void* const* d_in, const int* in_sizes, int n_in,
                              void* d_out, int out_size, void* d_ws, size_t ws_size,
                              hipStream_t stream) {
  const float* X    = (const float*)d_in[0];  // [8192,1024]
  const float* W    = (const float*)d_in[1];  // [1024,256]
  const float* bias = (const float*)d_in[2];  // [256]
  const float* adj  = (const float*)d_in[3];  // [8192,8192]
  float* out = (float*)d_out;                 // [8192,256]

  char* ws = (char*)d_ws;
  unsigned short* hb0  = (unsigned short*)(ws);                           // 4 MB
  unsigned short* hb1  = (unsigned short*)(ws + (size_t)4 * 1024 * 1024); // 4 MB
  unsigned short* hb2  = (unsigned short*)(ws + (size_t)8 * 1024 * 1024); // 4 MB
  float* dinv = (float*)(ws + (size_t)12 * 1024 * 1024);                  // 32 KB
  int*   nnz  = (int*)  (ws + (size_t)12 * 1024 * 1024 + 32 * 1024);      // 32 KB
  int*   cols = (int*)  (ws + (size_t)12 * 1024 * 1024 + 64 * 1024);      // 4 MB
  float* vals = (float*)(ws + (size_t)16 * 1024 * 1024 + 64 * 1024);      // 4 MB
  unsigned short* Wt = (unsigned short*)(ws + (size_t)20 * 1024 * 1024
                                            + 64 * 1024);                 // 512 KB
  unsigned int* cnt = (unsigned int*)(ws + (size_t)21 * 1024 * 1024);     // 4 B

  prep_wt<<<64, 256, 0, stream>>>(W, Wt, cnt);
  fused_extract_gemm<<<GEMM_BLOCKS + NNODES, 256, 0, stream>>>(
      X, Wt, bias, adj, hb0, dinv, nnz, cols, vals);
  prop_persist<<<PROP_BLOCKS, 256, 0, stream>>>(hb0, hb1, hb2, out, dinv,
                                                nnz, cols, vals, cnt);
}

// Round 14
// 138.860 us; speedup vs baseline: 7.5540x; 7.5540x over previous
//
#include <hip/hip_runtime.h>
#include <hip/hip_bf16.h>

#define NNODES 8192
#define EMB    1024
#define HID    256
#define MAXDEG 128

typedef float f32x4 __attribute__((ext_vector_type(4)));
typedef short bf16x8v __attribute__((ext_vector_type(8)));
typedef unsigned short u16x4 __attribute__((ext_vector_type(4)));
typedef unsigned short u16x8 __attribute__((ext_vector_type(8)));

static __device__ __forceinline__ unsigned short f2bf(float f) {
  union { float f; unsigned int u; } x; x.f = f;
  unsigned int r = (x.u + 0x7fffu + ((x.u >> 16) & 1u)) >> 16;
  return (unsigned short)r;
}
static __device__ __forceinline__ float bf2f(unsigned short u) {
  union { unsigned int u; float f; } x; x.u = ((unsigned int)u) << 16;
  return x.f;
}

// ---------------------------------------------------------------------------
// Fused: blocks [0,256) = bf16-MFMA GEMM 128x64 tile, B staged directly from
// W (f32, L2-resident) with inline transpose+bf16-convert -> prep_wt deleted.
// Blocks [256, 256+2048) = adjacency extract, ONE WAVE PER ROW with
// ballot/popc compaction (no LDS atomics, no syncthreads), nontemporal loads.
// h0 written as bf16.
// ---------------------------------------------------------------------------
#define GEMM_BLOCKS 256

__global__ __launch_bounds__(256) void fused_extract_gemm(
    const float* __restrict__ X, const float* __restrict__ W,
    const float* __restrict__ bias, const float* __restrict__ adj,
    unsigned short* __restrict__ hb0, float* __restrict__ dinv,
    int* __restrict__ nnz, int* __restrict__ cols, float* __restrict__ vals) {
  __shared__ char smem[24 * 1024 + 64];
  int t = threadIdx.x;
  int w = t >> 6, l = t & 63;

  if (blockIdx.x >= GEMM_BLOCKS) {
    // ---------------- extract path: one wave per adj row ----------------
    int row = (blockIdx.x - GEMM_BLOCKS) * 4 + w;
    const f32x4* arow = (const f32x4*)(adj + (size_t)row * NNODES);
    float sum = 0.f;
    int cnt = 0;
    int base = row * MAXDEG;
    for (int it = 0; it < NNODES / 4 / 64; it++) {   // 32 iters
      int c4 = it * 64 + l;
      f32x4 v = __builtin_nontemporal_load(arow + c4);
      sum += v.x + v.y + v.z + v.w;
#pragma unroll
      for (int e = 0; e < 4; e++) {
        float f = v[e];
        unsigned long long m = __ballot(f != 0.f);
        if (m) {                                   // wave-uniform branch
          if (f != 0.f) {
            int p = cnt + __popcll(m & ((1ull << l) - 1ull));
            if (p < MAXDEG) { cols[base + p] = c4 * 4 + e; vals[base + p] = f; }
          }
          cnt += __popcll(m);
        }
      }
    }
    for (int off = 32; off > 0; off >>= 1) sum += __shfl_down(sum, off, 64);
    if (l == 0) {
      dinv[row] = rsqrtf(sum);
      nnz[row] = (cnt > MAXDEG) ? MAXDEG : cnt;
    }
    return;
  }

  // ---------------- GEMM path: 128x64 tile, BK=64, bf16 MFMA ----------------
  unsigned short* As = (unsigned short*)smem;               // [128][64] bf16
  unsigned short* Bs = (unsigned short*)(smem + 16 * 1024); // [64n][64k] bf16
  int mb = blockIdx.x >> 2, nb = blockIdx.x & 3;   // X-stripe blocks adjacent
  int m0 = mb * 128, n0 = nb * 64;

  f32x4 acc[2][4] = {};

  for (int kt = 0; kt < EMB; kt += 64) {
    __syncthreads();
    // stage A: X[m0..+128][kt..+64] f32 -> bf16, swizzled
    {
      int c4 = t & 15;
#pragma unroll
      for (int rr = 0; rr < 8; rr++) {
        int row = rr * 16 + (t >> 4);
        float4 v = *(const float4*)&X[(size_t)(m0 + row) * EMB + kt + c4 * 4];
        u16x4 pk = {f2bf(v.x), f2bf(v.y), f2bf(v.z), f2bf(v.w)};
        int slot = ((c4 >> 1) + (row >> 1)) & 7;
        *(u16x4*)&As[row * 64 + slot * 8 + (c4 & 1) * 4] = pk;
      }
    }
    // stage B: W[kt..+64][n0..+64] f32 -> bf16, transposed into swizzled LDS
    // (write slot=((k>>3)+(n>>1))&7, pos k&7 — matches frag read k>>3=ks*4+(l>>4))
    {
#pragma unroll
      for (int p = 0; p < 4; p++) {
        int k = p * 16 + (t >> 4);
        int c4 = (t & 15) * 4;
        float4 v = *(const float4*)&W[(size_t)(kt + k) * HID + n0 + c4];
#pragma unroll
        for (int e = 0; e < 4; e++) {
          int n = c4 + e;
          float f = (e == 0) ? v.x : (e == 1) ? v.y : (e == 2) ? v.z : v.w;
          int slot = ((k >> 3) + (n >> 1)) & 7;
          Bs[n * 64 + slot * 8 + (k & 7)] = f2bf(f);
        }
      }
    }
    __syncthreads();
#pragma unroll
    for (int ks = 0; ks < 2; ks++) {
      bf16x8v a[2], b[4];
#pragma unroll
      for (int mf = 0; mf < 2; mf++) {
        int row = w * 32 + mf * 16 + (l & 15);
        int slot = ((ks * 4 + (l >> 4)) + (row >> 1)) & 7;
        a[mf] = *(bf16x8v*)&As[row * 64 + slot * 8];
      }
#pragma unroll
      for (int nf = 0; nf < 4; nf++) {
        int rowB = nf * 16 + (l & 15);
        int slot = ((ks * 4 + (l >> 4)) + (rowB >> 1)) & 7;
        b[nf] = *(bf16x8v*)&Bs[rowB * 64 + slot * 8];
      }
#pragma unroll
      for (int mf = 0; mf < 2; mf++)
#pragma unroll
        for (int nf = 0; nf < 4; nf++)
          acc[mf][nf] = __builtin_amdgcn_mfma_f32_16x16x32_bf16(a[mf], b[nf], acc[mf][nf], 0, 0, 0);
    }
  }
#pragma unroll
  for (int mf = 0; mf < 2; mf++)
#pragma unroll
    for (int nf = 0; nf < 4; nf++) {
      int r0 = m0 + w * 32 + mf * 16 + (l >> 4) * 4;
      int cc = n0 + nf * 16 + (l & 15);
      float bv = bias[cc];
#pragma unroll
      for (int r = 0; r < 4; r++)
        hb0[(size_t)(r0 + r) * HID + cc] = f2bf(fmaxf(acc[mf][nf][r] + bv, 0.f));
    }
}

// ---------------------------------------------------------------------------
// One APPNP step, bf16 storage / f32 accumulation, dinv folded on the fly:
// h_out[row,:] = 0.8*dinv[row]*sum_k val[row,k]*dinv[j]*h_in[j,:] + 0.2*h0[row,:]
// One wave per row; lane = 4 features.
// ---------------------------------------------------------------------------
__global__ __launch_bounds__(256) void prop_bf16(
    const unsigned short* __restrict__ h_in, const unsigned short* __restrict__ hb0,
    unsigned short* __restrict__ h_out, const float* __restrict__ dinv,
    const int* __restrict__ nnz, const int* __restrict__ cols,
    const float* __restrict__ vals) {
  int wave = threadIdx.x >> 6;
  int lane = threadIdx.x & 63;
  int row = blockIdx.x * 4 + wave;

  int n = nnz[row];
  int base = row * MAXDEG;

  float ax = 0.f, ay = 0.f, az = 0.f, aw = 0.f;
  for (int k = 0; k < n; k++) {
    int j = cols[base + k];
    float w = vals[base + k] * dinv[j];
    u16x4 hv = *(const u16x4*)&h_in[(size_t)j * HID + lane * 4];
    ax += w * bf2f(hv[0]); ay += w * bf2f(hv[1]);
    az += w * bf2f(hv[2]); aw += w * bf2f(hv[3]);
  }
  float s = 0.8f * dinv[row];
  u16x4 h0v = *(const u16x4*)&hb0[(size_t)row * HID + lane * 4];
  u16x4 o;
  o[0] = f2bf(s * ax + 0.2f * bf2f(h0v[0]));
  o[1] = f2bf(s * ay + 0.2f * bf2f(h0v[1]));
  o[2] = f2bf(s * az + 0.2f * bf2f(h0v[2]));
  o[3] = f2bf(s * aw + 0.2f * bf2f(h0v[3]));
  *(u16x4*)&h_out[(size_t)row * HID + lane * 4] = o;
}

// Final step: identical math, f32 output to d_out.
__global__ __launch_bounds__(256) void prop_final(
    const unsigned short* __restrict__ h_in, const unsigned short* __restrict__ hb0,
    float* __restrict__ out, const float* __restrict__ dinv,
    const int* __restrict__ nnz, const int* __restrict__ cols,
    const float* __restrict__ vals) {
  int wave = threadIdx.x >> 6;
  int lane = threadIdx.x & 63;
  int row = blockIdx.x * 4 + wave;

  int n = nnz[row];
  int base = row * MAXDEG;

  float ax = 0.f, ay = 0.f, az = 0.f, aw = 0.f;
  for (int k = 0; k < n; k++) {
    int j = cols[base + k];
    float w = vals[base + k] * dinv[j];
    u16x4 hv = *(const u16x4*)&h_in[(size_t)j * HID + lane * 4];
    ax += w * bf2f(hv[0]); ay += w * bf2f(hv[1]);
    az += w * bf2f(hv[2]); aw += w * bf2f(hv[3]);
  }
  float s = 0.8f * dinv[row];
  u16x4 h0v = *(const u16x4*)&hb0[(size_t)row * HID + lane * 4];
  float4 o;
  o.x = s * ax + 0.2f * bf2f(h0v[0]);
  o.y = s * ay + 0.2f * bf2f(h0v[1]);
  o.z = s * az + 0.2f * bf2f(h0v[2]);
  o.w = s * aw + 0.2f * bf2f(h0v[3]);
  *(float4*)&out[(size_t)row * HID + lane * 4] = o;
}

// ---------------------------------------------------------------------------
extern "C" void kernel_launch(void* const* d_in, const int* in_sizes, int n_in,
                              void* d_out, int out_size, void* d_ws, size_t ws_size,
                              hipStream_t stream) {
  const float* X    = (const float*)d_in[0];  // [8192,1024]
  const float* W    = (const float*)d_in[1];  // [1024,256]
  const float* bias = (const float*)d_in[2];  // [256]
  const float* adj  = (const float*)d_in[3];  // [8192,8192]
  float* out = (float*)d_out;                 // [8192,256]

  char* ws = (char*)d_ws;
  unsigned short* hb0  = (unsigned short*)(ws);                           // 4 MB
  unsigned short* hb1  = (unsigned short*)(ws + (size_t)4 * 1024 * 1024); // 4 MB
  unsigned short* hb2  = (unsigned short*)(ws + (size_t)8 * 1024 * 1024); // 4 MB
  float* dinv = (float*)(ws + (size_t)12 * 1024 * 1024);                  // 32 KB
  int*   nnz  = (int*)  (ws + (size_t)12 * 1024 * 1024 + 32 * 1024);      // 32 KB
  int*   cols = (int*)  (ws + (size_t)12 * 1024 * 1024 + 64 * 1024);      // 4 MB
  float* vals = (float*)(ws + (size_t)16 * 1024 * 1024 + 64 * 1024);      // 4 MB

  fused_extract_gemm<<<GEMM_BLOCKS + NNODES / 4, 256, 0, stream>>>(
      X, W, bias, adj, hb0, dinv, nnz, cols, vals);

  // 5 bf16 steps ping-ponging hb1/hb2, then final f32 step into d_out.
  prop_bf16<<<NNODES / 4, 256, 0, stream>>>(hb0, hb0, hb1, dinv, nnz, cols, vals);
  prop_bf16<<<NNODES / 4, 256, 0, stream>>>(hb1, hb0, hb2, dinv, nnz, cols, vals);
  prop_bf16<<<NNODES / 4, 256, 0, stream>>>(hb2, hb0, hb1, dinv, nnz, cols, vals);
  prop_bf16<<<NNODES / 4, 256, 0, stream>>>(hb1, hb0, hb2, dinv, nnz, cols, vals);
  prop_bf16<<<NNODES / 4, 256, 0, stream>>>(hb2, hb0, hb1, dinv, nnz, cols, vals);
  prop_final<<<NNODES / 4, 256, 0, stream>>>(hb1, hb0, out, dinv, nnz, cols, vals);
}

// Round 15
// 119.216 us; speedup vs baseline: 8.7987x; 1.1648x over previous
//
#include <hip/hip_runtime.h>
#include <hip/hip_bf16.h>

#define NNODES 8192
#define EMB    1024
#define HID    256
#define MAXDEG 128

typedef float f32x4 __attribute__((ext_vector_type(4)));
typedef short bf16x8v __attribute__((ext_vector_type(8)));
typedef unsigned short u16x4 __attribute__((ext_vector_type(4)));
typedef unsigned short u16x8 __attribute__((ext_vector_type(8)));

static __device__ __forceinline__ unsigned short f2bf(float f) {
  union { float f; unsigned int u; } x; x.f = f;
  unsigned int r = (x.u + 0x7fffu + ((x.u >> 16) & 1u)) >> 16;
  return (unsigned short)r;
}
static __device__ __forceinline__ float bf2f(unsigned short u) {
  union { unsigned int u; float f; } x; x.u = ((unsigned int)u) << 16;
  return x.f;
}

// ---------------------------------------------------------------------------
// Prep: Wt[n][k] = bf16(W[k][n]).  64x64 f32 tiles via LDS transpose. (R12)
// ---------------------------------------------------------------------------
__global__ __launch_bounds__(256) void prep_wt(const float* __restrict__ W,
                                               unsigned short* __restrict__ Wt) {
  __shared__ float lds[64 * 65];
  int k0 = (blockIdx.x >> 2) * 64;
  int n0 = (blockIdx.x & 3) * 64;
  int t = threadIdx.x;
#pragma unroll
  for (int p = 0; p < 4; p++) {
    int k = p * 16 + (t >> 4);
    int c4 = (t & 15) * 4;
    float4 v = *(const float4*)&W[(size_t)(k0 + k) * HID + n0 + c4];
    lds[k * 65 + c4 + 0] = v.x; lds[k * 65 + c4 + 1] = v.y;
    lds[k * 65 + c4 + 2] = v.z; lds[k * 65 + c4 + 3] = v.w;
  }
  __syncthreads();
  int n = t >> 2, kq = t & 3;
  u16x8 o0, o1;
#pragma unroll
  for (int i = 0; i < 8; i++) o0[i] = f2bf(lds[(kq * 16 + i) * 65 + n]);
#pragma unroll
  for (int i = 0; i < 8; i++) o1[i] = f2bf(lds[(kq * 16 + 8 + i) * 65 + n]);
  unsigned short* dst = &Wt[(size_t)(n0 + n) * EMB + k0 + kq * 16];
  *(u16x8*)(dst) = o0;
  *(u16x8*)(dst + 8) = o1;
}

// ---------------------------------------------------------------------------
// Fused (R12 + batched extract loads): blocks [0,256) = bf16-MFMA GEMM
// 128x64 tile; blocks [256, 256+8192) = extract — all 8 nontemporal f32x4
// loads issued to registers BEFORE the atomic-bearing processing loop
// (the LDS atomic otherwise serializes the stream).
// ---------------------------------------------------------------------------
#define GEMM_BLOCKS 256

__global__ __launch_bounds__(256) void fused_extract_gemm(
    const float* __restrict__ X, const unsigned short* __restrict__ Wt,
    const float* __restrict__ bias, const float* __restrict__ adj,
    unsigned short* __restrict__ hb0, float* __restrict__ dinv,
    int* __restrict__ nnz, int* __restrict__ cols, float* __restrict__ vals) {
  __shared__ char smem[24 * 1024 + 64];
  int t = threadIdx.x;

  if (blockIdx.x >= GEMM_BLOCKS) {
    // ---------------- extract path ----------------
    int row = blockIdx.x - GEMM_BLOCKS;
    int* s_cnt = (int*)smem;
    float* s_part = (float*)(smem + 16);
    if (t == 0) *s_cnt = 0;
    __syncthreads();
    const f32x4* arow = (const f32x4*)(adj + (size_t)row * NNODES);
    int base = row * MAXDEG;

    f32x4 v[8];
#pragma unroll
    for (int i = 0; i < 8; i++)
      v[i] = __builtin_nontemporal_load(arow + i * 256 + t);

    float sum = 0.f;
#pragma unroll
    for (int i = 0; i < 8; i++) {
      sum += v[i].x + v[i].y + v[i].z + v[i].w;
      int j0 = (i * 256 + t) * 4;
      if (v[i].x != 0.f) { int p = atomicAdd(s_cnt, 1); if (p < MAXDEG) { cols[base + p] = j0 + 0; vals[base + p] = v[i].x; } }
      if (v[i].y != 0.f) { int p = atomicAdd(s_cnt, 1); if (p < MAXDEG) { cols[base + p] = j0 + 1; vals[base + p] = v[i].y; } }
      if (v[i].z != 0.f) { int p = atomicAdd(s_cnt, 1); if (p < MAXDEG) { cols[base + p] = j0 + 2; vals[base + p] = v[i].z; } }
      if (v[i].w != 0.f) { int p = atomicAdd(s_cnt, 1); if (p < MAXDEG) { cols[base + p] = j0 + 3; vals[base + p] = v[i].w; } }
    }
    for (int off = 32; off > 0; off >>= 1) sum += __shfl_down(sum, off, 64);
    int wave = t >> 6;
    if ((t & 63) == 0) s_part[wave] = sum;
    __syncthreads();
    if (t == 0) {
      float tot = s_part[0] + s_part[1] + s_part[2] + s_part[3];
      dinv[row] = rsqrtf(tot);
      int c = *s_cnt;
      nnz[row] = (c > MAXDEG) ? MAXDEG : c;
    }
    return;
  }

  // ---------------- GEMM path: 128x64 tile, BK=64, bf16 MFMA (R12) ---------
  unsigned short* As = (unsigned short*)smem;               // [128][64] bf16
  unsigned short* Bs = (unsigned short*)(smem + 16 * 1024); // [64][64] bf16 (B^T)
  int mb = blockIdx.x >> 2, nb = blockIdx.x & 3;
  int m0 = mb * 128, n0 = nb * 64;
  int w = t >> 6, l = t & 63;

  f32x4 acc[2][4] = {};

  for (int kt = 0; kt < EMB; kt += 64) {
    __syncthreads();
    {
      int c4 = t & 15;
#pragma unroll
      for (int rr = 0; rr < 8; rr++) {
        int row = rr * 16 + (t >> 4);
        float4 v = *(const float4*)&X[(size_t)(m0 + row) * EMB + kt + c4 * 4];
        u16x4 pk = {f2bf(v.x), f2bf(v.y), f2bf(v.z), f2bf(v.w)};
        int slot = ((c4 >> 1) + (row >> 1)) & 7;
        *(u16x4*)&As[row * 64 + slot * 8 + (c4 & 1) * 4] = pk;
      }
    }
    {
      int n = t >> 2, q = t & 3;
      const unsigned short* src = &Wt[(size_t)(n0 + n) * EMB + kt + q * 16];
#pragma unroll
      for (int e = 0; e < 2; e++) {
        u16x8 v = *(const u16x8*)(src + e * 8);
        int slot = ((q * 2 + e) + (n >> 1)) & 7;
        *(u16x8*)&Bs[n * 64 + slot * 8] = v;
      }
    }
    __syncthreads();
#pragma unroll
    for (int ks = 0; ks < 2; ks++) {
      bf16x8v a[2], b[4];
#pragma unroll
      for (int mf = 0; mf < 2; mf++) {
        int row = w * 32 + mf * 16 + (l & 15);
        int slot = ((ks * 4 + (l >> 4)) + (row >> 1)) & 7;
        a[mf] = *(bf16x8v*)&As[row * 64 + slot * 8];
      }
#pragma unroll
      for (int nf = 0; nf < 4; nf++) {
        int rowB = nf * 16 + (l & 15);
        int slot = ((ks * 4 + (l >> 4)) + (rowB >> 1)) & 7;
        b[nf] = *(bf16x8v*)&Bs[rowB * 64 + slot * 8];
      }
#pragma unroll
      for (int mf = 0; mf < 2; mf++)
#pragma unroll
        for (int nf = 0; nf < 4; nf++)
          acc[mf][nf] = __builtin_amdgcn_mfma_f32_16x16x32_bf16(a[mf], b[nf], acc[mf][nf], 0, 0, 0);
    }
  }
#pragma unroll
  for (int mf = 0; mf < 2; mf++)
#pragma unroll
    for (int nf = 0; nf < 4; nf++) {
      int r0 = m0 + w * 32 + mf * 16 + (l >> 4) * 4;
      int cc = n0 + nf * 16 + (l & 15);
      float bv = bias[cc];
#pragma unroll
      for (int r = 0; r < 4; r++)
        hb0[(size_t)(r0 + r) * HID + cc] = f2bf(fmaxf(acc[mf][nf][r] + bv, 0.f));
    }
}

// ---------------------------------------------------------------------------
// One APPNP step, bf16/f32, dinv folded, EDGE-PREFETCHED (n<=4 fast path:
// int4/float4 metadata load, padded slots clamped to own row with w=0 —
// poison-safe, value-identical). Serial tail for rare n>4 rows.
// ---------------------------------------------------------------------------
__global__ __launch_bounds__(256) void prop_bf16(
    const unsigned short* __restrict__ h_in, const unsigned short* __restrict__ hb0,
    unsigned short* __restrict__ h_out, const float* __restrict__ dinv,
    const int* __restrict__ nnz, const int* __restrict__ cols,
    const float* __restrict__ vals) {
  int wave = threadIdx.x >> 6;
  int lane = threadIdx.x & 63;
  int row = blockIdx.x * 4 + wave;

  int n = nnz[row];
  int base = row * MAXDEG;

  u16x4 h0v = *(const u16x4*)&hb0[(size_t)row * HID + lane * 4];
  int4   cv = *(const int4*)&cols[base];
  float4 vv = *(const float4*)&vals[base];

  int jj[4]; float ww[4];
  jj[0] = (0 < n) ? cv.x : row;  ww[0] = (0 < n) ? vv.x : 0.f;
  jj[1] = (1 < n) ? cv.y : row;  ww[1] = (1 < n) ? vv.y : 0.f;
  jj[2] = (2 < n) ? cv.z : row;  ww[2] = (2 < n) ? vv.z : 0.f;
  jj[3] = (3 < n) ? cv.w : row;  ww[3] = (3 < n) ? vv.w : 0.f;

  float ax = 0.f, ay = 0.f, az = 0.f, aw = 0.f;
#pragma unroll
  for (int k = 0; k < 4; k++) {
    float wgt = ww[k] * dinv[jj[k]];
    u16x4 hv = *(const u16x4*)&h_in[(size_t)jj[k] * HID + lane * 4];
    ax += wgt * bf2f(hv[0]); ay += wgt * bf2f(hv[1]);
    az += wgt * bf2f(hv[2]); aw += wgt * bf2f(hv[3]);
  }
  for (int k = 4; k < n; k++) {          // rare
    int j = cols[base + k];
    float wgt = vals[base + k] * dinv[j];
    u16x4 hv = *(const u16x4*)&h_in[(size_t)j * HID + lane * 4];
    ax += wgt * bf2f(hv[0]); ay += wgt * bf2f(hv[1]);
    az += wgt * bf2f(hv[2]); aw += wgt * bf2f(hv[3]);
  }
  float s = 0.8f * dinv[row];
  u16x4 o;
  o[0] = f2bf(s * ax + 0.2f * bf2f(h0v[0]));
  o[1] = f2bf(s * ay + 0.2f * bf2f(h0v[1]));
  o[2] = f2bf(s * az + 0.2f * bf2f(h0v[2]));
  o[3] = f2bf(s * aw + 0.2f * bf2f(h0v[3]));
  *(u16x4*)&h_out[(size_t)row * HID + lane * 4] = o;
}

// Final step: identical math, f32 output to d_out.
__global__ __launch_bounds__(256) void prop_final(
    const unsigned short* __restrict__ h_in, const unsigned short* __restrict__ hb0,
    float* __restrict__ out, const float* __restrict__ dinv,
    const int* __restrict__ nnz, const int* __restrict__ cols,
    const float* __restrict__ vals) {
  int wave = threadIdx.x >> 6;
  int lane = threadIdx.x & 63;
  int row = blockIdx.x * 4 + wave;

  int n = nnz[row];
  int base = row * MAXDEG;

  u16x4 h0v = *(const u16x4*)&hb0[(size_t)row * HID + lane * 4];
  int4   cv = *(const int4*)&cols[base];
  float4 vv = *(const float4*)&vals[base];

  int jj[4]; float ww[4];
  jj[0] = (0 < n) ? cv.x : row;  ww[0] = (0 < n) ? vv.x : 0.f;
  jj[1] = (1 < n) ? cv.y : row;  ww[1] = (1 < n) ? vv.y : 0.f;
  jj[2] = (2 < n) ? cv.z : row;  ww[2] = (2 < n) ? vv.z : 0.f;
  jj[3] = (3 < n) ? cv.w : row;  ww[3] = (3 < n) ? vv.w : 0.f;

  float ax = 0.f, ay = 0.f, az = 0.f, aw = 0.f;
#pragma unroll
  for (int k = 0; k < 4; k++) {
    float wgt = ww[k] * dinv[jj[k]];
    u16x4 hv = *(const u16x4*)&h_in[(size_t)jj[k] * HID + lane * 4];
    ax += wgt * bf2f(hv[0]); ay += wgt * bf2f(hv[1]);
    az += wgt * bf2f(hv[2]); aw += wgt * bf2f(hv[3]);
  }
  for (int k = 4; k < n; k++) {          // rare
    int j = cols[base + k];
    float wgt = vals[base + k] * dinv[j];
    u16x4 hv = *(const u16x4*)&h_in[(size_t)j * HID + lane * 4];
    ax += wgt * bf2f(hv[0]); ay += wgt * bf2f(hv[1]);
    az += wgt * bf2f(hv[2]); aw += wgt * bf2f(hv[3]);
  }
  float s = 0.8f * dinv[row];
  float4 o;
  o.x = s * ax + 0.2f * bf2f(h0v[0]);
  o.y = s * ay + 0.2f * bf2f(h0v[1]);
  o.z = s * az + 0.2f * bf2f(h0v[2]);
  o.w = s * aw + 0.2f * bf2f(h0v[3]);
  *(float4*)&out[(size_t)row * HID + lane * 4] = o;
}

// ---------------------------------------------------------------------------
extern "C" void kernel_launch(void* const* d_in, const int* in_sizes, int n_in,
                              void* d_out, int out_size, void* d_ws, size_t ws_size,
                              hipStream_t stream) {
  const float* X    = (const float*)d_in[0];  // [8192,1024]
  const float* W    = (const float*)d_in[1];  // [1024,256]
  const float* bias = (const float*)d_in[2];  // [256]
  const float* adj  = (const float*)d_in[3];  // [8192,8192]
  float* out = (float*)d_out;                 // [8192,256]

  char* ws = (char*)d_ws;
  unsigned short* hb0  = (unsigned short*)(ws);                           // 4 MB
  unsigned short* hb1  = (unsigned short*)(ws + (size_t)4 * 1024 * 1024); // 4 MB
  unsigned short* hb2  = (unsigned short*)(ws + (size_t)8 * 1024 * 1024); // 4 MB
  float* dinv = (float*)(ws + (size_t)12 * 1024 * 1024);                  // 32 KB
  int*   nnz  = (int*)  (ws + (size_t)12 * 1024 * 1024 + 32 * 1024);      // 32 KB
  int*   cols = (int*)  (ws + (size_t)12 * 1024 * 1024 + 64 * 1024);      // 4 MB
  float* vals = (float*)(ws + (size_t)16 * 1024 * 1024 + 64 * 1024);      // 4 MB
  unsigned short* Wt = (unsigned short*)(ws + (size_t)20 * 1024 * 1024
                                            + 64 * 1024);                 // 512 KB

  prep_wt<<<64, 256, 0, stream>>>(W, Wt);
  fused_extract_gemm<<<GEMM_BLOCKS + NNODES, 256, 0, stream>>>(
      X, Wt, bias, adj, hb0, dinv, nnz, cols, vals);

  // 5 bf16 steps ping-ponging hb1/hb2, then final f32 step into d_out.
  prop_bf16<<<NNODES / 4, 256, 0, stream>>>(hb0, hb0, hb1, dinv, nnz, cols, vals);
  prop_bf16<<<NNODES / 4, 256, 0, stream>>>(hb1, hb0, hb2, dinv, nnz, cols, vals);
  prop_bf16<<<NNODES / 4, 256, 0, stream>>>(hb2, hb0, hb1, dinv, nnz, cols, vals);
  prop_bf16<<<NNODES / 4, 256, 0, stream>>>(hb1, hb0, hb2, dinv, nnz, cols, vals);
  prop_bf16<<<NNODES / 4, 256, 0, stream>>>(hb2, hb0, hb1, dinv, nnz, cols, vals);
  prop_final<<<NNODES / 4, 256, 0, stream>>>(hb1, hb0, out, dinv, nnz, cols, vals);
}